// Round 8
// baseline (146.249 us; speedup 1.0000x reference)
//
#include <hip/hip_runtime.h>
#include <stdint.h>

#define B_ 8
#define N_ 4096
#define D_ 512
#define INV_T 0.04419417382415922f  // 1/sqrt(512)

typedef unsigned short u16;
typedef float f32x4 __attribute__((ext_vector_type(4)));
typedef __bf16 bf16x4 __attribute__((ext_vector_type(4)));
typedef __bf16 bf16x8 __attribute__((ext_vector_type(8)));
typedef unsigned short u16x8 __attribute__((ext_vector_type(8)));

__device__ __forceinline__ u16 f2bf(float x) {
  union { float f; uint32_t u; } c;
  c.f = x;
  uint32_t r = c.u + 0x7FFFu + ((c.u >> 16) & 1u);
  return (u16)(r >> 16);
}

__device__ __forceinline__ void load_lds16(const u16* g, u16* l) {
  __builtin_amdgcn_global_load_lds(
      (__attribute__((address_space(1))) void*)(g),
      (__attribute__((address_space(3))) void*)(l), 16, 0, 0);
}

// Fused transpose+gemm1: Sp[kz*8+b][d][e] = sum_{n in slice} k[b][n][d]*v[b][n][e]
// Split-K=4. 3-buffer LDS rotation, ONE barrier/step, 2-step-deep register
// prefetch (loads for kt+2 issued at kt; cvt/LDS-write of kt+1 after the
// fragment reads -> ~2-step load->use window). XCD-swizzled 1D grid.
__global__ __launch_bounds__(256) void k_gemm1f(const float* __restrict__ kin,
                                                const float* __restrict__ vin,
                                                float* __restrict__ Sp) {
  __shared__ u16 As[3][128 * 32];  // [d_local][n_local], write-XOR-swizzled
  __shared__ u16 Bs[3][128 * 32];
  const int flat = blockIdx.x;  // 0..511
  const int swz = (flat & 7) * 64 + (flat >> 3);
  const int z = swz >> 4;                      // 0..31
  const int bm = (swz >> 2) & 3, bn = swz & 3;
  const int b = z & 7, kz = z >> 3;            // split-K = 4, 1024 n per slice
  const int tid = threadIdx.x;
  const int wave = tid >> 6, lane = tid & 63;
  const int wr = wave >> 1, wc = wave & 1;
  const int lrow = lane & 15, lk = (lane >> 4) * 8;
  const int c = tid & 31, G = tid >> 5;  // c: d-chunk (4 cols), G: n-group
  const float* ga = kin + (size_t)b * N_ * D_ + (size_t)(kz * 1024 + 4 * G) * D_ +
                    bm * 128 + 4 * c;
  const float* gb = vin + (size_t)b * N_ * D_ + (size_t)(kz * 1024 + 4 * G) * D_ +
                    bn * 128 + 4 * c;
  float* C = Sp + (size_t)z * ((size_t)D_ * D_);

  const f32x4 fzero = {0.f, 0.f, 0.f, 0.f};
  f32x4 acc[4][4];
#pragma unroll
  for (int m = 0; m < 4; ++m)
#pragma unroll
    for (int n = 0; n < 4; ++n) acc[m][n] = fzero;

  f32x4 rA[2][4], rB[2][4];
  // prologue: step0 -> regset0 -> buf0; step1 -> regset1
#pragma unroll
  for (int j = 0; j < 4; ++j) {
    rA[0][j] = *(const f32x4*)(ga + (size_t)j * D_);
    rB[0][j] = *(const f32x4*)(gb + (size_t)j * D_);
  }
  {
    bf16x4 wav[4], wbv[4];
#pragma unroll
    for (int i = 0; i < 4; ++i)
#pragma unroll
      for (int j = 0; j < 4; ++j) {
        wav[i][j] = (__bf16)rA[0][j][i];
        wbv[i][j] = (__bf16)rB[0][j][i];
      }
#pragma unroll
    for (int i = 0; i < 4; ++i) {
      const int sidx = ((4 * c + i) * 32 + 4 * G) ^ ((c & 7) << 3);
      *(bf16x4*)(As[0] + sidx) = wav[i];
      *(bf16x4*)(Bs[0] + sidx) = wbv[i];
    }
  }
#pragma unroll
  for (int j = 0; j < 4; ++j) {
    rA[1][j] = *(const f32x4*)(ga + (size_t)(32 + j) * D_);
    rB[1][j] = *(const f32x4*)(gb + (size_t)(32 + j) * D_);
  }

  int cur = 0;
  for (int kt = 0; kt < 32; ++kt) {
    __syncthreads();  // buf[cur] writes (from iter kt-1 / prologue) visible
    // earliest: issue loads for step kt+2 into regset[kt&1] (just cvt'd at kt-1)
    if (kt + 2 < 32) {
#pragma unroll
      for (int j = 0; j < 4; ++j) {
        rA[kt & 1][j] = *(const f32x4*)(ga + (size_t)((kt + 2) * 32 + j) * D_);
        rB[kt & 1][j] = *(const f32x4*)(gb + (size_t)((kt + 2) * 32 + j) * D_);
      }
    }
    const u16* Ac = As[cur];
    const u16* Bc = Bs[cur];
    bf16x8 af[4], bfv[4];
#pragma unroll
    for (int m = 0; m < 4; ++m) {
      const int row = wr * 64 + m * 16 + lrow;
      af[m] = *(const bf16x8*)(Ac + ((row * 32 + lk) ^ (((row >> 2) & 7) << 3)));
    }
#pragma unroll
    for (int n = 0; n < 4; ++n) {
      const int row = wc * 64 + n * 16 + lrow;
      bfv[n] = *(const bf16x8*)(Bc + ((row * 32 + lk) ^ (((row >> 2) & 7) << 3)));
    }
    int nxt = cur + 1;
    if (nxt == 3) nxt = 0;
    if (kt + 1 < 32) {
      // cvt regs of step kt+1 (loaded at kt-1: ~2 steps in flight) -> buf[nxt].
      // buf[nxt] was last read at iter kt-2: two barriers back -> laggard-safe.
      bf16x4 wav[4], wbv[4];
#pragma unroll
      for (int i = 0; i < 4; ++i)
#pragma unroll
        for (int j = 0; j < 4; ++j) {
          wav[i][j] = (__bf16)rA[(kt + 1) & 1][j][i];
          wbv[i][j] = (__bf16)rB[(kt + 1) & 1][j][i];
        }
#pragma unroll
      for (int i = 0; i < 4; ++i) {
        const int sidx = ((4 * c + i) * 32 + 4 * G) ^ ((c & 7) << 3);
        *(bf16x4*)(As[nxt] + sidx) = wav[i];
        *(bf16x4*)(Bs[nxt] + sidx) = wbv[i];
      }
    }
#pragma unroll
    for (int m = 0; m < 4; ++m)
#pragma unroll
      for (int n = 0; n < 4; ++n)
        acc[m][n] = __builtin_amdgcn_mfma_f32_16x16x32_bf16(af[m], bfv[n],
                                                            acc[m][n], 0, 0, 0);
    cur = nxt;
  }
  // C/D layout (m89-verified): row = (lane>>4)*4 + reg, col = lane&15
  const int crow = (lane >> 4) * 4, ccol = lane & 15;
#pragma unroll
  for (int m = 0; m < 4; ++m) {
    const int grow = bm * 128 + wr * 64 + m * 16 + crow;
#pragma unroll
    for (int n = 0; n < 4; ++n) {
      const int gcol = bn * 128 + wc * 64 + n * 16 + ccol;
#pragma unroll
      for (int i2 = 0; i2 < 4; ++i2)
        C[(size_t)(grow + i2) * D_ + gcol] = acc[m][n][i2];
    }
  }
}

// Sum 4 split-K partials, scale by 1/T, softmax rows, write attn fp32.
__global__ __launch_bounds__(256) void k_softmax(const float* __restrict__ Sp,
                                                 float* __restrict__ attn) {
  const int t = threadIdx.x;
  const int wave = t >> 6, lane = t & 63;
  const int g = blockIdx.x * 4 + wave;  // 0..4095 rows
  const int b = g >> 9, d = g & 511;
  const float* base = Sp + (size_t)b * (D_ * D_) + (size_t)d * D_ + lane * 8;
  float s[8];
#pragma unroll
  for (int jj = 0; jj < 8; ++jj) s[jj] = 0.f;
#pragma unroll
  for (int kz = 0; kz < 4; ++kz) {
    const f32x4 p0 = *(const f32x4*)(base + (size_t)kz * 8 * (D_ * D_));
    const f32x4 p1 = *(const f32x4*)(base + (size_t)kz * 8 * (D_ * D_) + 4);
#pragma unroll
    for (int jj = 0; jj < 4; ++jj) { s[jj] += p0[jj]; s[4 + jj] += p1[jj]; }
  }
#pragma unroll
  for (int jj = 0; jj < 8; ++jj) s[jj] *= INV_T;  // temperature
  float mx = s[0];
#pragma unroll
  for (int jj = 1; jj < 8; ++jj) mx = fmaxf(mx, s[jj]);
  for (int o = 32; o > 0; o >>= 1) mx = fmaxf(mx, __shfl_xor(mx, o));
  float sum = 0.f;
#pragma unroll
  for (int jj = 0; jj < 8; ++jj) { s[jj] = __expf(s[jj] - mx); sum += s[jj]; }
  for (int o = 32; o > 0; o >>= 1) sum += __shfl_xor(sum, o);
  const float inv = 1.0f / sum;
  float* orow = attn + (size_t)b * (D_ * D_) + (size_t)d * D_ + lane * 8;
  f32x4 o0, o1;
#pragma unroll
  for (int jj = 0; jj < 4; ++jj) { o0[jj] = s[jj] * inv; o1[jj] = s[4 + jj] * inv; }
  *(f32x4*)orow = o0;
  *(f32x4*)(orow + 4) = o1;
}

// attn fp32 [b][d][e] -> attnT bf16 [b][e][d]
__global__ __launch_bounds__(256) void k_attn_t(const float* __restrict__ attn,
                                                u16* __restrict__ attnT) {
  __shared__ float lds[64][65];
  const int t = threadIdx.x;
  const int b = blockIdx.z;
  const float* src = attn + (size_t)b * D_ * D_;
  u16* dst = attnT + (size_t)b * D_ * D_;
  const int d0 = blockIdx.x * 64, e0 = blockIdx.y * 64;
#pragma unroll
  for (int i = 0; i < 4; ++i) {
    const int fidx = i * 256 + t;
    const int r = fidx >> 4, c4 = fidx & 15;
    const f32x4 f = *(const f32x4*)(src + (size_t)(d0 + r) * D_ + e0 + c4 * 4);
#pragma unroll
    for (int jj = 0; jj < 4; ++jj) lds[r][c4 * 4 + jj] = f[jj];
  }
  __syncthreads();
#pragma unroll
  for (int j = 0; j < 2; ++j) {
    const int sidx = j * 256 + t;
    const int rd = sidx >> 3, c8 = sidx & 7;
    u16x8 o;
#pragma unroll
    for (int jj = 0; jj < 8; ++jj) o[jj] = f2bf(lds[c8 * 8 + jj][rd]);
    *(u16x8*)(dst + (size_t)(e0 + rd) * D_ + d0 + c8 * 8) = o;
  }
}

// gemm2: out[b][n][e] = sum_d v[b][n][d] * attnT[b][e][d]
// 3-buffer rotation, one barrier/step; A reg-staged 2-deep; B via
// global_load_lds issued one buffer ahead (drained by the barrier).
// XCD swizzle: batch b -> XCD b (A-panel L2 reuse across bn).
__global__ __launch_bounds__(256) void k_gemm2(const float* __restrict__ v,
                                               const u16* __restrict__ attnT,
                                               float* __restrict__ out) {
  __shared__ u16 As[3][128 * 32];
  __shared__ u16 Bs[3][128 * 32];
  const int flat = blockIdx.x;  // 0..1023
  const int swz = (flat & 7) * 128 + (flat >> 3);
  const int b = swz >> 7;
  const int rem = swz & 127;
  const int bm = rem & 31, bn = rem >> 5;
  const float* Ab = v + (size_t)b * ((size_t)N_ * D_) + (size_t)(bm * 128) * D_;
  const u16* Bb = attnT + (size_t)b * ((size_t)D_ * D_) + (size_t)(bn * 128) * D_;
  float* C = out + (size_t)b * ((size_t)N_ * D_);
  const int tid = threadIdx.x;
  const int wave = tid >> 6, lane = tid & 63;
  const int wr = wave >> 1, wc = wave & 1;
  const int lrow = lane & 15, lk = (lane >> 4) * 8;
  const int srow = lane >> 2, scol = (lane & 3) * 8;
  const int arow0 = tid >> 2, ac8 = tid & 3;  // A-staging: 4 threads/row
  const f32x4 fzero = {0.f, 0.f, 0.f, 0.f};
  f32x4 acc[4][4];
#pragma unroll
  for (int m = 0; m < 4; ++m)
#pragma unroll
    for (int n = 0; n < 4; ++n) acc[m][n] = fzero;

  f32x4 rf[2][4];  // [set][i*2+half]: rows i*64+arow0, 8 f32 each
  // prologue: A step0 -> set0 -> As[0]; B step0 -> Bs[0]; A step1 -> set1
#pragma unroll
  for (int i = 0; i < 2; ++i) {
    const int row = i * 64 + arow0;
    rf[0][i * 2] = *(const f32x4*)(Ab + (size_t)row * D_ + ac8 * 8);
    rf[0][i * 2 + 1] = *(const f32x4*)(Ab + (size_t)row * D_ + ac8 * 8 + 4);
  }
#pragma unroll
  for (int i = 0; i < 2; ++i) {
    const int row = i * 64 + arow0;
    bf16x8 o;
#pragma unroll
    for (int jj = 0; jj < 4; ++jj) {
      o[jj] = (__bf16)rf[0][i * 2][jj];
      o[4 + jj] = (__bf16)rf[0][i * 2 + 1][jj];
    }
    *(bf16x8*)(As[0] + row * 32 + ac8 * 8) = o;
  }
#pragma unroll
  for (int i = 0; i < 2; ++i) {
    const int cc = i * 4 + wave;
    load_lds16(Bb + (size_t)(cc * 16 + srow) * D_ + scol, Bs[0] + cc * 512);
  }
#pragma unroll
  for (int i = 0; i < 2; ++i) {
    const int row = i * 64 + arow0;
    rf[1][i * 2] = *(const f32x4*)(Ab + (size_t)row * D_ + 32 + ac8 * 8);
    rf[1][i * 2 + 1] = *(const f32x4*)(Ab + (size_t)row * D_ + 32 + ac8 * 8 + 4);
  }

  int cur = 0;
  for (int kt = 0; kt < 16; ++kt) {
    __syncthreads();  // As[cur]/Bs[cur] ready (B DMA drained by barrier's vmcnt)
    if (kt + 2 < 16) {
#pragma unroll
      for (int i = 0; i < 2; ++i) {
        const int row = i * 64 + arow0;
        rf[kt & 1][i * 2] =
            *(const f32x4*)(Ab + (size_t)row * D_ + (kt + 2) * 32 + ac8 * 8);
        rf[kt & 1][i * 2 + 1] =
            *(const f32x4*)(Ab + (size_t)row * D_ + (kt + 2) * 32 + ac8 * 8 + 4);
      }
    }
    int nxt = cur + 1;
    if (nxt == 3) nxt = 0;
    if (kt + 1 < 16) {  // B DMA for kt+1 -> Bs[nxt] (last read at kt-2: safe)
#pragma unroll
      for (int i = 0; i < 2; ++i) {
        const int cc = i * 4 + wave;
        load_lds16(Bb + (size_t)(cc * 16 + srow) * D_ + (kt + 1) * 32 + scol,
                   Bs[nxt] + cc * 512);
      }
    }
    const u16* Ac = As[cur];
    const u16* Bc = Bs[cur];
    bf16x8 af[4], bfv[4];
#pragma unroll
    for (int m = 0; m < 4; ++m)
      af[m] = *(const bf16x8*)(Ac + (wr * 64 + m * 16 + lrow) * 32 + lk);
#pragma unroll
    for (int n = 0; n < 4; ++n)
      bfv[n] = *(const bf16x8*)(Bc + (wc * 64 + n * 16 + lrow) * 32 + lk);
    if (kt + 1 < 16) {  // cvt step kt+1 regs (2 steps in flight) -> As[nxt]
#pragma unroll
      for (int i = 0; i < 2; ++i) {
        const int row = i * 64 + arow0;
        bf16x8 o;
#pragma unroll
        for (int jj = 0; jj < 4; ++jj) {
          o[jj] = (__bf16)rf[(kt + 1) & 1][i * 2][jj];
          o[4 + jj] = (__bf16)rf[(kt + 1) & 1][i * 2 + 1][jj];
        }
        *(bf16x8*)(As[nxt] + row * 32 + ac8 * 8) = o;
      }
    }
#pragma unroll
    for (int m = 0; m < 4; ++m)
#pragma unroll
      for (int n = 0; n < 4; ++n)
        acc[m][n] = __builtin_amdgcn_mfma_f32_16x16x32_bf16(af[m], bfv[n],
                                                            acc[m][n], 0, 0, 0);
    cur = nxt;
  }
  const int crow = (lane >> 4) * 4, ccol = lane & 15;
#pragma unroll
  for (int m = 0; m < 4; ++m) {
    const int grow = bm * 128 + wr * 64 + m * 16 + crow;
#pragma unroll
    for (int n = 0; n < 4; ++n) {
      const int gcol = bn * 128 + wc * 64 + n * 16 + ccol;
#pragma unroll
      for (int i2 = 0; i2 < 4; ++i2)
        C[(size_t)(grow + i2) * D_ + gcol] = acc[m][n][i2];
    }
  }
}

extern "C" void kernel_launch(void* const* d_in, const int* in_sizes, int n_in,
                              void* d_out, int out_size, void* d_ws, size_t ws_size,
                              hipStream_t stream) {
  const float* v = (const float*)d_in[0];
  const float* k = (const float*)d_in[1];
  float* out = (float*)d_out;                        // [8][4096][512] fp32, 64 MiB
  float* attn = out + (size_t)B_ * N_ * D_;          // [8][512][512] fp32, 8 MiB
  // Split-K partials: 4 x [8][512][512] f32 = 32 MiB in the out region
  // (dead until gemm2 overwrites it).
  float* Sp = (float*)d_out;
  u16* attnT = (u16*)d_ws;                           // [8][512][512] bf16, 4 MiB

  k_gemm1f<<<dim3(512), dim3(256), 0, stream>>>(k, v, Sp);
  k_softmax<<<dim3(1024), dim3(256), 0, stream>>>(Sp, attn);
  k_attn_t<<<dim3(8, 8, 8), dim3(256), 0, stream>>>(attn, attnT);
  k_gemm2<<<dim3(1024), dim3(256), 0, stream>>>(v, attnT, out);
}

// Round 11
// 88.893 us; speedup vs baseline: 1.6452x; 1.6452x over previous
//
#include <hip/hip_runtime.h>
#include <stdint.h>

#define B_ 8
#define N_ 4096
#define D_ 512
#define INV_T 0.04419417382415922f  // 1/sqrt(512)

typedef unsigned short u16;
typedef float f32x4 __attribute__((ext_vector_type(4)));
typedef __bf16 bf16x4 __attribute__((ext_vector_type(4)));
typedef __bf16 bf16x8 __attribute__((ext_vector_type(8)));
typedef unsigned short u16x8 __attribute__((ext_vector_type(8)));

__device__ __forceinline__ u16 f2bf(float x) {
  union { float f; uint32_t u; } c;
  c.f = x;
  uint32_t r = c.u + 0x7FFFu + ((c.u >> 16) & 1u);
  return (u16)(r >> 16);
}

__device__ __forceinline__ void load_lds16(const u16* g, u16* l) {
  __builtin_amdgcn_global_load_lds(
      (__attribute__((address_space(1))) void*)(g),
      (__attribute__((address_space(3))) void*)(l), 16, 0, 0);
}

// Fused transpose+gemm1: Sp[kz*8+b][d][e] = sum_{n in slice} k[b][n][d]*v[b][n][e]
// Split-K=4, XCD-swizzled. 2-buffer LDS, ONE barrier/step, manual 2x unroll
// with NAMED register sets. Write swizzle computed PER ELEMENT (r10 bug: the
// XOR mask (bits 3-5) does not commute with +i*32 (bit 5) — never hoist it).
__global__ __launch_bounds__(256) void k_gemm1f(const float* __restrict__ kin,
                                                const float* __restrict__ vin,
                                                float* __restrict__ Sp) {
  __shared__ u16 As[2][128 * 32];  // [d_local][n_local], write-XOR-swizzled
  __shared__ u16 Bs[2][128 * 32];
  const int flat = blockIdx.x;  // 0..511
  const int swz = (flat & 7) * 64 + (flat >> 3);
  const int z = swz >> 4;                      // 0..31
  const int bm = (swz >> 2) & 3, bn = swz & 3;
  const int b = z & 7, kz = z >> 3;            // split-K = 4, 1024 n per slice
  const int tid = threadIdx.x;
  const int wave = tid >> 6, lane = tid & 63;
  const int wr = wave >> 1, wc = wave & 1;
  const int lrow = lane & 15, lk = (lane >> 4) * 8;
  const int c = tid & 31, G = tid >> 5;  // c: d-chunk (4 cols), G: n-group
  const float* ga = kin + (size_t)b * N_ * D_ + (size_t)(kz * 1024 + 4 * G) * D_ +
                    bm * 128 + 4 * c;
  const float* gb = vin + (size_t)b * N_ * D_ + (size_t)(kz * 1024 + 4 * G) * D_ +
                    bn * 128 + 4 * c;
  float* C = Sp + (size_t)z * ((size_t)D_ * D_);

  const f32x4 fzero = {0.f, 0.f, 0.f, 0.f};
  f32x4 acc[4][4];
#pragma unroll
  for (int m = 0; m < 4; ++m)
#pragma unroll
    for (int n = 0; n < 4; ++n) acc[m][n] = fzero;

  f32x4 sA0[4], sB0[4], sA1[4], sB1[4];  // named prefetch sets (static idx)

#define LOADSET(SET_A, SET_B, STEP)                                        \
  {                                                                        \
    _Pragma("unroll") for (int j = 0; j < 4; ++j) {                        \
      SET_A[j] = *(const f32x4*)(ga + (size_t)((STEP)*32 + j) * D_);       \
      SET_B[j] = *(const f32x4*)(gb + (size_t)((STEP)*32 + j) * D_);       \
    }                                                                      \
  }
#define CVTSET(SET_A, SET_B, BUF)                                          \
  {                                                                        \
    bf16x4 wav[4], wbv[4];                                                 \
    _Pragma("unroll") for (int i = 0; i < 4; ++i)                          \
        _Pragma("unroll") for (int j = 0; j < 4; ++j) {                    \
      wav[i][j] = (__bf16)SET_A[j][i];                                     \
      wbv[i][j] = (__bf16)SET_B[j][i];                                     \
    }                                                                      \
    _Pragma("unroll") for (int i = 0; i < 4; ++i) {                        \
      const int sidx = ((4 * c + i) * 32 + 4 * G) ^ ((c & 7) << 3);        \
      *(bf16x4*)(As[BUF] + sidx) = wav[i];                                 \
      *(bf16x4*)(Bs[BUF] + sidx) = wbv[i];                                 \
    }                                                                      \
  }
#define FRAGS_MFMA(BUF)                                                    \
  {                                                                        \
    bf16x8 af[4], bfv[4];                                                  \
    _Pragma("unroll") for (int m = 0; m < 4; ++m) {                        \
      const int row = wr * 64 + m * 16 + lrow;                             \
      af[m] = *(const bf16x8*)(As[BUF] +                                   \
                               ((row * 32 + lk) ^ (((row >> 2) & 7) << 3)));\
    }                                                                      \
    _Pragma("unroll") for (int n = 0; n < 4; ++n) {                        \
      const int row = wc * 64 + n * 16 + lrow;                             \
      bfv[n] = *(const bf16x8*)(Bs[BUF] +                                  \
                                ((row * 32 + lk) ^ (((row >> 2) & 7) << 3)));\
    }                                                                      \
    _Pragma("unroll") for (int m = 0; m < 4; ++m)                          \
        _Pragma("unroll") for (int n = 0; n < 4; ++n) acc[m][n] =          \
            __builtin_amdgcn_mfma_f32_16x16x32_bf16(af[m], bfv[n],         \
                                                    acc[m][n], 0, 0, 0);   \
  }

  // prologue: step0 -> set0 -> buf0; step1 -> set1
  LOADSET(sA0, sB0, 0)
  CVTSET(sA0, sB0, 0)
  LOADSET(sA1, sB1, 1)

  for (int m2 = 0; m2 < 16; ++m2) {
    const int t = 2 * m2;
    // EVEN step t: consume buf0 (holds step t)
    __syncthreads();
    if (t + 2 < 32) LOADSET(sA0, sB0, t + 2)  // set0 free: its data is in LDS
    CVTSET(sA1, sB1, 1)                       // step t+1 -> buf1
    FRAGS_MFMA(0)
    // ODD step t+1: consume buf1
    __syncthreads();
    if (t + 3 < 32) LOADSET(sA1, sB1, t + 3)
    if (t + 2 < 32) CVTSET(sA0, sB0, 0)       // step t+2 -> buf0 (laggard-safe:
                                              // readers of buf0 passed barrier)
    FRAGS_MFMA(1)
  }
#undef LOADSET
#undef CVTSET
#undef FRAGS_MFMA

  // C/D layout (m89-verified): row = (lane>>4)*4 + reg, col = lane&15
  const int crow = (lane >> 4) * 4, ccol = lane & 15;
#pragma unroll
  for (int m = 0; m < 4; ++m) {
    const int grow = bm * 128 + wr * 64 + m * 16 + crow;
#pragma unroll
    for (int n = 0; n < 4; ++n) {
      const int gcol = bn * 128 + wc * 64 + n * 16 + ccol;
#pragma unroll
      for (int i2 = 0; i2 < 4; ++i2)
        C[(size_t)(grow + i2) * D_ + gcol] = acc[m][n][i2];
    }
  }
}

// Sum 4 split-K partials, scale by 1/T, softmax rows, write attn fp32.
__global__ __launch_bounds__(256) void k_softmax(const float* __restrict__ Sp,
                                                 float* __restrict__ attn) {
  const int t = threadIdx.x;
  const int wave = t >> 6, lane = t & 63;
  const int g = blockIdx.x * 4 + wave;  // 0..4095 rows
  const int b = g >> 9, d = g & 511;
  const float* base = Sp + (size_t)b * (D_ * D_) + (size_t)d * D_ + lane * 8;
  float s[8];
#pragma unroll
  for (int jj = 0; jj < 8; ++jj) s[jj] = 0.f;
#pragma unroll
  for (int kz = 0; kz < 4; ++kz) {
    const f32x4 p0 = *(const f32x4*)(base + (size_t)kz * 8 * (D_ * D_));
    const f32x4 p1 = *(const f32x4*)(base + (size_t)kz * 8 * (D_ * D_) + 4);
#pragma unroll
    for (int jj = 0; jj < 4; ++jj) { s[jj] += p0[jj]; s[4 + jj] += p1[jj]; }
  }
#pragma unroll
  for (int jj = 0; jj < 8; ++jj) s[jj] *= INV_T;  // temperature
  float mx = s[0];
#pragma unroll
  for (int jj = 1; jj < 8; ++jj) mx = fmaxf(mx, s[jj]);
  for (int o = 32; o > 0; o >>= 1) mx = fmaxf(mx, __shfl_xor(mx, o));
  float sum = 0.f;
#pragma unroll
  for (int jj = 0; jj < 8; ++jj) { s[jj] = __expf(s[jj] - mx); sum += s[jj]; }
  for (int o = 32; o > 0; o >>= 1) sum += __shfl_xor(sum, o);
  const float inv = 1.0f / sum;
  float* orow = attn + (size_t)b * (D_ * D_) + (size_t)d * D_ + lane * 8;
  f32x4 o0, o1;
#pragma unroll
  for (int jj = 0; jj < 4; ++jj) { o0[jj] = s[jj] * inv; o1[jj] = s[4 + jj] * inv; }
  *(f32x4*)orow = o0;
  *(f32x4*)(orow + 4) = o1;
}

// attn fp32 [b][d][e] -> attnT bf16 [b][e][d]
__global__ __launch_bounds__(256) void k_attn_t(const float* __restrict__ attn,
                                                u16* __restrict__ attnT) {
  __shared__ float lds[64][65];
  const int t = threadIdx.x;
  const int b = blockIdx.z;
  const float* src = attn + (size_t)b * D_ * D_;
  u16* dst = attnT + (size_t)b * D_ * D_;
  const int d0 = blockIdx.x * 64, e0 = blockIdx.y * 64;
#pragma unroll
  for (int i = 0; i < 4; ++i) {
    const int fidx = i * 256 + t;
    const int r = fidx >> 4, c4 = fidx & 15;
    const f32x4 f = *(const f32x4*)(src + (size_t)(d0 + r) * D_ + e0 + c4 * 4);
#pragma unroll
    for (int jj = 0; jj < 4; ++jj) lds[r][c4 * 4 + jj] = f[jj];
  }
  __syncthreads();
#pragma unroll
  for (int j = 0; j < 2; ++j) {
    const int sidx = j * 256 + t;
    const int rd = sidx >> 3, c8 = sidx & 7;
    u16x8 o;
#pragma unroll
    for (int jj = 0; jj < 8; ++jj) o[jj] = f2bf(lds[c8 * 8 + jj][rd]);
    *(u16x8*)(dst + (size_t)(e0 + rd) * D_ + d0 + c8 * 8) = o;
  }
}

// gemm2: out[b][n][e] = sum_d v[b][n][d] * attnT[b][e][d]
// Double-buffered LDS, one barrier per step (r6-proven version).
__global__ __launch_bounds__(256) void k_gemm2(const float* __restrict__ v,
                                               const u16* __restrict__ attnT,
                                               float* __restrict__ out) {
  __shared__ u16 As[2][128 * 32];
  __shared__ u16 Bs[2][128 * 32];
  const int bm = blockIdx.x, bn = blockIdx.y, b = blockIdx.z;
  const float* Ab = v + (size_t)b * ((size_t)N_ * D_) + (size_t)(bm * 128) * D_;
  const u16* Bb = attnT + (size_t)b * ((size_t)D_ * D_) + (size_t)(bn * 128) * D_;
  float* C = out + (size_t)b * ((size_t)N_ * D_);
  const int tid = threadIdx.x;
  const int wave = tid >> 6, lane = tid & 63;
  const int wr = wave >> 1, wc = wave & 1;
  const int lrow = lane & 15, lk = (lane >> 4) * 8;
  const int srow = lane >> 2, scol = (lane & 3) * 8;
  const int arow0 = tid >> 2, ac8 = tid & 3;  // A-staging: 4 threads/row
  const f32x4 fzero = {0.f, 0.f, 0.f, 0.f};
  f32x4 acc[4][4];
#pragma unroll
  for (int m = 0; m < 4; ++m)
#pragma unroll
    for (int n = 0; n < 4; ++n) acc[m][n] = fzero;

  f32x4 rf0[2], rf1[2];
#pragma unroll
  for (int i = 0; i < 2; ++i) {
    const int row = i * 64 + arow0;
    rf0[i] = *(const f32x4*)(Ab + (size_t)row * D_ + ac8 * 8);
    rf1[i] = *(const f32x4*)(Ab + (size_t)row * D_ + ac8 * 8 + 4);
  }

  for (int kt = 0; kt < 16; ++kt) {
    const int k0 = kt * 32;
    u16* Ad = As[kt & 1];
    u16* Bd = Bs[kt & 1];
    // B first: max slack before the barrier's vmcnt drain
#pragma unroll
    for (int i = 0; i < 2; ++i) {
      const int cc = i * 4 + wave;
      load_lds16(Bb + (size_t)(cc * 16 + srow) * D_ + k0 + scol, Bd + cc * 512);
    }
    // A: cvt staged regs -> one b128 write per thread per chunk
#pragma unroll
    for (int i = 0; i < 2; ++i) {
      const int row = i * 64 + arow0;
      bf16x8 o;
#pragma unroll
      for (int jj = 0; jj < 4; ++jj) {
        o[jj] = (__bf16)rf0[i][jj];
        o[4 + jj] = (__bf16)rf1[i][jj];
      }
      *(bf16x8*)(Ad + row * 32 + ac8 * 8) = o;
    }
    if (kt + 1 < 16) {
#pragma unroll
      for (int i = 0; i < 2; ++i) {
        const int row = i * 64 + arow0;
        rf0[i] = *(const f32x4*)(Ab + (size_t)row * D_ + (k0 + 32) + ac8 * 8);
        rf1[i] = *(const f32x4*)(Ab + (size_t)row * D_ + (k0 + 32) + ac8 * 8 + 4);
      }
    }
    __syncthreads();
    bf16x8 af[4], bfv[4];
#pragma unroll
    for (int m = 0; m < 4; ++m)
      af[m] = *(const bf16x8*)(Ad + (wr * 64 + m * 16 + lrow) * 32 + lk);
#pragma unroll
    for (int n = 0; n < 4; ++n)
      bfv[n] = *(const bf16x8*)(Bd + (wc * 64 + n * 16 + lrow) * 32 + lk);
#pragma unroll
    for (int m = 0; m < 4; ++m)
#pragma unroll
      for (int n = 0; n < 4; ++n)
        acc[m][n] = __builtin_amdgcn_mfma_f32_16x16x32_bf16(af[m], bfv[n],
                                                            acc[m][n], 0, 0, 0);
  }
  const int crow = (lane >> 4) * 4, ccol = lane & 15;
#pragma unroll
  for (int m = 0; m < 4; ++m) {
    const int grow = bm * 128 + wr * 64 + m * 16 + crow;
#pragma unroll
    for (int n = 0; n < 4; ++n) {
      const int gcol = bn * 128 + wc * 64 + n * 16 + ccol;
#pragma unroll
      for (int i2 = 0; i2 < 4; ++i2)
        C[(size_t)(grow + i2) * D_ + gcol] = acc[m][n][i2];
    }
  }
}

extern "C" void kernel_launch(void* const* d_in, const int* in_sizes, int n_in,
                              void* d_out, int out_size, void* d_ws, size_t ws_size,
                              hipStream_t stream) {
  const float* v = (const float*)d_in[0];
  const float* k = (const float*)d_in[1];
  float* out = (float*)d_out;                        // [8][4096][512] fp32, 64 MiB
  float* attn = out + (size_t)B_ * N_ * D_;          // [8][512][512] fp32, 8 MiB
  // Split-K partials: 4 x [8][512][512] f32 = 32 MiB in the out region
  // (dead until gemm2 overwrites it).
  float* Sp = (float*)d_out;
  u16* attnT = (u16*)d_ws;                           // [8][512][512] bf16, 4 MiB

  k_gemm1f<<<dim3(512), dim3(256), 0, stream>>>(k, v, Sp);
  k_softmax<<<dim3(1024), dim3(256), 0, stream>>>(Sp, attn);
  k_attn_t<<<dim3(8, 8, 8), dim3(256), 0, stream>>>(attn, attnT);
  k_gemm2<<<dim3(32, 4, 8), dim3(256), 0, stream>>>(v, attnT, out);
}

// Round 12
// 85.671 us; speedup vs baseline: 1.7071x; 1.0376x over previous
//
#include <hip/hip_runtime.h>
#include <stdint.h>

#define B_ 8
#define N_ 4096
#define D_ 512
#define INV_T 0.04419417382415922f  // 1/sqrt(512)

typedef unsigned short u16;
typedef float f32x4 __attribute__((ext_vector_type(4)));
typedef __bf16 bf16x4 __attribute__((ext_vector_type(4)));
typedef __bf16 bf16x8 __attribute__((ext_vector_type(8)));
typedef unsigned short u16x8 __attribute__((ext_vector_type(8)));

__device__ __forceinline__ u16 f2bf(float x) {
  union { float f; uint32_t u; } c;
  c.f = x;
  uint32_t r = c.u + 0x7FFFu + ((c.u >> 16) & 1u);
  return (u16)(r >> 16);
}

__device__ __forceinline__ void load_lds16(const u16* g, u16* l) {
  __builtin_amdgcn_global_load_lds(
      (__attribute__((address_space(1))) void*)(g),
      (__attribute__((address_space(3))) void*)(l), 16, 0, 0);
}

// Raw barrier: drain ONLY lgkm (ds_writes) — leave prefetch global loads
// in flight across the barrier (T4 counted-vmcnt; __syncthreads would
// emit vmcnt(0) and chop the 2-step prefetch window).
__device__ __forceinline__ void barrier_lgkm_only() {
  asm volatile("s_waitcnt lgkmcnt(0)" ::: "memory");
  __builtin_amdgcn_sched_barrier(0);
  __builtin_amdgcn_s_barrier();
  __builtin_amdgcn_sched_barrier(0);
}

// Fused transpose+gemm1: Sp[kz*8+b][d][e] = sum_{n in slice} k[b][n][d]*v[b][n][e]
// Split-K=4, XCD-swizzled. 2-buffer LDS, ONE lgkm-only barrier/step, manual
// 2x unroll with NAMED register sets; prefetch loads stay in flight across
// barriers and are awaited only by the compiler's counted vmcnt at the cvt.
__global__ __launch_bounds__(256) void k_gemm1f(const float* __restrict__ kin,
                                                const float* __restrict__ vin,
                                                float* __restrict__ Sp) {
  __shared__ u16 As[2][128 * 32];  // [d_local][n_local], write-XOR-swizzled
  __shared__ u16 Bs[2][128 * 32];
  const int flat = blockIdx.x;  // 0..511
  const int swz = (flat & 7) * 64 + (flat >> 3);
  const int z = swz >> 4;                      // 0..31
  const int bm = (swz >> 2) & 3, bn = swz & 3;
  const int b = z & 7, kz = z >> 3;            // split-K = 4, 1024 n per slice
  const int tid = threadIdx.x;
  const int wave = tid >> 6, lane = tid & 63;
  const int wr = wave >> 1, wc = wave & 1;
  const int lrow = lane & 15, lk = (lane >> 4) * 8;
  const int c = tid & 31, G = tid >> 5;  // c: d-chunk (4 cols), G: n-group
  const float* ga = kin + (size_t)b * N_ * D_ + (size_t)(kz * 1024 + 4 * G) * D_ +
                    bm * 128 + 4 * c;
  const float* gb = vin + (size_t)b * N_ * D_ + (size_t)(kz * 1024 + 4 * G) * D_ +
                    bn * 128 + 4 * c;
  float* C = Sp + (size_t)z * ((size_t)D_ * D_);

  const f32x4 fzero = {0.f, 0.f, 0.f, 0.f};
  f32x4 acc[4][4];
#pragma unroll
  for (int m = 0; m < 4; ++m)
#pragma unroll
    for (int n = 0; n < 4; ++n) acc[m][n] = fzero;

  f32x4 sA0[4], sB0[4], sA1[4], sB1[4];  // named prefetch sets (static idx)

#define LOADSET(SET_A, SET_B, STEP)                                        \
  {                                                                        \
    _Pragma("unroll") for (int j = 0; j < 4; ++j) {                        \
      SET_A[j] = *(const f32x4*)(ga + (size_t)((STEP)*32 + j) * D_);       \
      SET_B[j] = *(const f32x4*)(gb + (size_t)((STEP)*32 + j) * D_);       \
    }                                                                      \
  }
#define CVTSET(SET_A, SET_B, BUF)                                          \
  {                                                                        \
    bf16x4 wav[4], wbv[4];                                                 \
    _Pragma("unroll") for (int i = 0; i < 4; ++i)                          \
        _Pragma("unroll") for (int j = 0; j < 4; ++j) {                    \
      wav[i][j] = (__bf16)SET_A[j][i];                                     \
      wbv[i][j] = (__bf16)SET_B[j][i];                                     \
    }                                                                      \
    _Pragma("unroll") for (int i = 0; i < 4; ++i) {                        \
      const int sidx = ((4 * c + i) * 32 + 4 * G) ^ ((c & 7) << 3);        \
      *(bf16x4*)(As[BUF] + sidx) = wav[i];                                 \
      *(bf16x4*)(Bs[BUF] + sidx) = wbv[i];                                 \
    }                                                                      \
  }
#define FRAGS_MFMA(BUF)                                                    \
  {                                                                        \
    bf16x8 af[4], bfv[4];                                                  \
    _Pragma("unroll") for (int m = 0; m < 4; ++m) {                        \
      const int row = wr * 64 + m * 16 + lrow;                             \
      af[m] = *(const bf16x8*)(As[BUF] +                                   \
                               ((row * 32 + lk) ^ (((row >> 2) & 7) << 3)));\
    }                                                                      \
    _Pragma("unroll") for (int n = 0; n < 4; ++n) {                        \
      const int row = wc * 64 + n * 16 + lrow;                             \
      bfv[n] = *(const bf16x8*)(Bs[BUF] +                                  \
                                ((row * 32 + lk) ^ (((row >> 2) & 7) << 3)));\
    }                                                                      \
    _Pragma("unroll") for (int m = 0; m < 4; ++m)                          \
        _Pragma("unroll") for (int n = 0; n < 4; ++n) acc[m][n] =          \
            __builtin_amdgcn_mfma_f32_16x16x32_bf16(af[m], bfv[n],         \
                                                    acc[m][n], 0, 0, 0);   \
  }

  // prologue: step0 -> set0 -> buf0; step1 -> set1
  LOADSET(sA0, sB0, 0)
  CVTSET(sA0, sB0, 0)
  LOADSET(sA1, sB1, 1)

  for (int m2 = 0; m2 < 16; ++m2) {
    const int t = 2 * m2;
    // EVEN step t: consume buf0 (holds step t)
    barrier_lgkm_only();
    if (t + 2 < 32) LOADSET(sA0, sB0, t + 2)  // set0 free: its data is in LDS
    CVTSET(sA1, sB1, 1)                       // step t+1 -> buf1
    FRAGS_MFMA(0)
    // ODD step t+1: consume buf1
    barrier_lgkm_only();
    if (t + 3 < 32) LOADSET(sA1, sB1, t + 3)
    if (t + 2 < 32) CVTSET(sA0, sB0, 0)       // step t+2 -> buf0 (laggard-safe:
                                              // readers of buf0 passed barrier)
    FRAGS_MFMA(1)
  }
#undef LOADSET
#undef CVTSET
#undef FRAGS_MFMA

  // C/D layout (m89-verified): row = (lane>>4)*4 + reg, col = lane&15
  const int crow = (lane >> 4) * 4, ccol = lane & 15;
#pragma unroll
  for (int m = 0; m < 4; ++m) {
    const int grow = bm * 128 + wr * 64 + m * 16 + crow;
#pragma unroll
    for (int n = 0; n < 4; ++n) {
      const int gcol = bn * 128 + wc * 64 + n * 16 + ccol;
#pragma unroll
      for (int i2 = 0; i2 < 4; ++i2)
        C[(size_t)(grow + i2) * D_ + gcol] = acc[m][n][i2];
    }
  }
}

// Sum 4 split-K partials, scale by 1/T, softmax rows, write attn fp32.
__global__ __launch_bounds__(256) void k_softmax(const float* __restrict__ Sp,
                                                 float* __restrict__ attn) {
  const int t = threadIdx.x;
  const int wave = t >> 6, lane = t & 63;
  const int g = blockIdx.x * 4 + wave;  // 0..4095 rows
  const int b = g >> 9, d = g & 511;
  const float* base = Sp + (size_t)b * (D_ * D_) + (size_t)d * D_ + lane * 8;
  float s[8];
#pragma unroll
  for (int jj = 0; jj < 8; ++jj) s[jj] = 0.f;
#pragma unroll
  for (int kz = 0; kz < 4; ++kz) {
    const f32x4 p0 = *(const f32x4*)(base + (size_t)kz * 8 * (D_ * D_));
    const f32x4 p1 = *(const f32x4*)(base + (size_t)kz * 8 * (D_ * D_) + 4);
#pragma unroll
    for (int jj = 0; jj < 4; ++jj) { s[jj] += p0[jj]; s[4 + jj] += p1[jj]; }
  }
#pragma unroll
  for (int jj = 0; jj < 8; ++jj) s[jj] *= INV_T;  // temperature
  float mx = s[0];
#pragma unroll
  for (int jj = 1; jj < 8; ++jj) mx = fmaxf(mx, s[jj]);
  for (int o = 32; o > 0; o >>= 1) mx = fmaxf(mx, __shfl_xor(mx, o));
  float sum = 0.f;
#pragma unroll
  for (int jj = 0; jj < 8; ++jj) { s[jj] = __expf(s[jj] - mx); sum += s[jj]; }
  for (int o = 32; o > 0; o >>= 1) sum += __shfl_xor(sum, o);
  const float inv = 1.0f / sum;
  float* orow = attn + (size_t)b * (D_ * D_) + (size_t)d * D_ + lane * 8;
  f32x4 o0, o1;
#pragma unroll
  for (int jj = 0; jj < 4; ++jj) { o0[jj] = s[jj] * inv; o1[jj] = s[4 + jj] * inv; }
  *(f32x4*)orow = o0;
  *(f32x4*)(orow + 4) = o1;
}

// attn fp32 [b][d][e] -> attnT bf16 [b][e][d]
__global__ __launch_bounds__(256) void k_attn_t(const float* __restrict__ attn,
                                                u16* __restrict__ attnT) {
  __shared__ float lds[64][65];
  const int t = threadIdx.x;
  const int b = blockIdx.z;
  const float* src = attn + (size_t)b * D_ * D_;
  u16* dst = attnT + (size_t)b * D_ * D_;
  const int d0 = blockIdx.x * 64, e0 = blockIdx.y * 64;
#pragma unroll
  for (int i = 0; i < 4; ++i) {
    const int fidx = i * 256 + t;
    const int r = fidx >> 4, c4 = fidx & 15;
    const f32x4 f = *(const f32x4*)(src + (size_t)(d0 + r) * D_ + e0 + c4 * 4);
#pragma unroll
    for (int jj = 0; jj < 4; ++jj) lds[r][c4 * 4 + jj] = f[jj];
  }
  __syncthreads();
#pragma unroll
  for (int j = 0; j < 2; ++j) {
    const int sidx = j * 256 + t;
    const int rd = sidx >> 3, c8 = sidx & 7;
    u16x8 o;
#pragma unroll
    for (int jj = 0; jj < 8; ++jj) o[jj] = f2bf(lds[c8 * 8 + jj][rd]);
    *(u16x8*)(dst + (size_t)(e0 + rd) * D_ + d0 + c8 * 8) = o;
  }
}

// gemm2: out[b][n][e] = sum_d v[b][n][d] * attnT[b][e][d]
// Double-buffered LDS, one barrier per step (r6-proven version; keeps
// __syncthreads — its B-DMA is consumed right after the barrier, so the
// vmcnt drain is required here).
__global__ __launch_bounds__(256) void k_gemm2(const float* __restrict__ v,
                                               const u16* __restrict__ attnT,
                                               float* __restrict__ out) {
  __shared__ u16 As[2][128 * 32];
  __shared__ u16 Bs[2][128 * 32];
  const int bm = blockIdx.x, bn = blockIdx.y, b = blockIdx.z;
  const float* Ab = v + (size_t)b * ((size_t)N_ * D_) + (size_t)(bm * 128) * D_;
  const u16* Bb = attnT + (size_t)b * ((size_t)D_ * D_) + (size_t)(bn * 128) * D_;
  float* C = out + (size_t)b * ((size_t)N_ * D_);
  const int tid = threadIdx.x;
  const int wave = tid >> 6, lane = tid & 63;
  const int wr = wave >> 1, wc = wave & 1;
  const int lrow = lane & 15, lk = (lane >> 4) * 8;
  const int srow = lane >> 2, scol = (lane & 3) * 8;
  const int arow0 = tid >> 2, ac8 = tid & 3;  // A-staging: 4 threads/row
  const f32x4 fzero = {0.f, 0.f, 0.f, 0.f};
  f32x4 acc[4][4];
#pragma unroll
  for (int m = 0; m < 4; ++m)
#pragma unroll
    for (int n = 0; n < 4; ++n) acc[m][n] = fzero;

  f32x4 rf0[2], rf1[2];
#pragma unroll
  for (int i = 0; i < 2; ++i) {
    const int row = i * 64 + arow0;
    rf0[i] = *(const f32x4*)(Ab + (size_t)row * D_ + ac8 * 8);
    rf1[i] = *(const f32x4*)(Ab + (size_t)row * D_ + ac8 * 8 + 4);
  }

  for (int kt = 0; kt < 16; ++kt) {
    const int k0 = kt * 32;
    u16* Ad = As[kt & 1];
    u16* Bd = Bs[kt & 1];
    // B first: max slack before the barrier's vmcnt drain
#pragma unroll
    for (int i = 0; i < 2; ++i) {
      const int cc = i * 4 + wave;
      load_lds16(Bb + (size_t)(cc * 16 + srow) * D_ + k0 + scol, Bd + cc * 512);
    }
    // A: cvt staged regs -> one b128 write per thread per chunk
#pragma unroll
    for (int i = 0; i < 2; ++i) {
      const int row = i * 64 + arow0;
      bf16x8 o;
#pragma unroll
      for (int jj = 0; jj < 4; ++jj) {
        o[jj] = (__bf16)rf0[i][jj];
        o[4 + jj] = (__bf16)rf1[i][jj];
      }
      *(bf16x8*)(Ad + row * 32 + ac8 * 8) = o;
    }
    if (kt + 1 < 16) {
#pragma unroll
      for (int i = 0; i < 2; ++i) {
        const int row = i * 64 + arow0;
        rf0[i] = *(const f32x4*)(Ab + (size_t)row * D_ + (k0 + 32) + ac8 * 8);
        rf1[i] = *(const f32x4*)(Ab + (size_t)row * D_ + (k0 + 32) + ac8 * 8 + 4);
      }
    }
    __syncthreads();
    bf16x8 af[4], bfv[4];
#pragma unroll
    for (int m = 0; m < 4; ++m)
      af[m] = *(const bf16x8*)(Ad + (wr * 64 + m * 16 + lrow) * 32 + lk);
#pragma unroll
    for (int n = 0; n < 4; ++n)
      bfv[n] = *(const bf16x8*)(Bd + (wc * 64 + n * 16 + lrow) * 32 + lk);
#pragma unroll
    for (int m = 0; m < 4; ++m)
#pragma unroll
      for (int n = 0; n < 4; ++n)
        acc[m][n] = __builtin_amdgcn_mfma_f32_16x16x32_bf16(af[m], bfv[n],
                                                            acc[m][n], 0, 0, 0);
  }
  const int crow = (lane >> 4) * 4, ccol = lane & 15;
#pragma unroll
  for (int m = 0; m < 4; ++m) {
    const int grow = bm * 128 + wr * 64 + m * 16 + crow;
#pragma unroll
    for (int n = 0; n < 4; ++n) {
      const int gcol = bn * 128 + wc * 64 + n * 16 + ccol;
#pragma unroll
      for (int i2 = 0; i2 < 4; ++i2)
        C[(size_t)(grow + i2) * D_ + gcol] = acc[m][n][i2];
    }
  }
}

extern "C" void kernel_launch(void* const* d_in, const int* in_sizes, int n_in,
                              void* d_out, int out_size, void* d_ws, size_t ws_size,
                              hipStream_t stream) {
  const float* v = (const float*)d_in[0];
  const float* k = (const float*)d_in[1];
  float* out = (float*)d_out;                        // [8][4096][512] fp32, 64 MiB
  float* attn = out + (size_t)B_ * N_ * D_;          // [8][512][512] fp32, 8 MiB
  // Split-K partials: 4 x [8][512][512] f32 = 32 MiB in the out region
  // (dead until gemm2 overwrites it).
  float* Sp = (float*)d_out;
  u16* attnT = (u16*)d_ws;                           // [8][512][512] bf16, 4 MiB

  k_gemm1f<<<dim3(512), dim3(256), 0, stream>>>(k, v, Sp);
  k_softmax<<<dim3(1024), dim3(256), 0, stream>>>(Sp, attn);
  k_attn_t<<<dim3(8, 8, 8), dim3(256), 0, stream>>>(attn, attnT);
  k_gemm2<<<dim3(32, 4, 8), dim3(256), 0, stream>>>(v, attnT, out);
}